// Round 3
// baseline (744.654 us; speedup 1.0000x reference)
//
#include <hip/hip_runtime.h>

// ROI adaptive avg-pool 7x7, direct summation, one thread per (channel, oy).
// x: [B=8, C=64, H=256, W=256] f32;  rois: [B, S=128, 5] i32 (idx,x1,y1,x2,y2)
// out: [B, S*C, 7, 7] f32 = out[((b*S+s)*C+c)*49 + oy*7+ox]
//
// Layout: block = one roi (b,s); 448 threads = 7 waves; thread t -> c = t&63,
// oy = t>>6. Within a wave oy and all bin bounds are wave-uniform -> zero
// divergence; 7 independent accumulators give 7-way MLP per thread.

constexpr int OUT_HW = 7;
constexpr int BINS = OUT_HW * OUT_HW;
constexpr int C = 64;

__global__ __launch_bounds__(448) void roi_pool(
    const float* __restrict__ x, const int* __restrict__ rois,
    float* __restrict__ out, int H, int W)
{
    const int bs = blockIdx.x;          // b*S + s, S = 128
    const int b  = bs >> 7;
    const int* r = rois + bs * 5;
    const int x1 = r[1], y1 = r[2], x2 = r[3], y2 = r[4];
    const int w = x2 - x1, h = y2 - y1;

    __shared__ int s_sy[OUT_HW], s_ey[OUT_HW], s_sx[OUT_HW], s_ex[OUT_HW];
    if (threadIdx.x < OUT_HW) {
        const int i = threadIdx.x;
        s_sy[i] = y1 + (i * h) / OUT_HW;
        s_ey[i] = y1 + ((i + 1) * h + OUT_HW - 1) / OUT_HW;
        s_sx[i] = x1 + (i * w) / OUT_HW;
        s_ex[i] = x1 + ((i + 1) * w + OUT_HW - 1) / OUT_HW;
    }
    __syncthreads();

    const int t  = threadIdx.x;
    const int c  = t & 63;
    const int oy = t >> 6;              // wave-uniform

    const int sy = s_sy[oy], ey = s_ey[oy];
    const float* __restrict__ p = x + ((size_t)b * C + c) * H * W;

    float acc0 = 0.f, acc1 = 0.f, acc2 = 0.f, acc3 = 0.f,
          acc4 = 0.f, acc5 = 0.f, acc6 = 0.f;

    for (int yy = sy; yy < ey; ++yy) {
        const float* __restrict__ row = p + yy * W;
        float a;
        a = 0.f; for (int xx = s_sx[0]; xx < s_ex[0]; ++xx) a += row[xx]; acc0 += a;
        a = 0.f; for (int xx = s_sx[1]; xx < s_ex[1]; ++xx) a += row[xx]; acc1 += a;
        a = 0.f; for (int xx = s_sx[2]; xx < s_ex[2]; ++xx) a += row[xx]; acc2 += a;
        a = 0.f; for (int xx = s_sx[3]; xx < s_ex[3]; ++xx) a += row[xx]; acc3 += a;
        a = 0.f; for (int xx = s_sx[4]; xx < s_ex[4]; ++xx) a += row[xx]; acc4 += a;
        a = 0.f; for (int xx = s_sx[5]; xx < s_ex[5]; ++xx) a += row[xx]; acc5 += a;
        a = 0.f; for (int xx = s_sx[6]; xx < s_ex[6]; ++xx) a += row[xx]; acc6 += a;
    }

    const float ry = 1.0f / (float)(ey - sy);
    float* __restrict__ o = out + ((size_t)bs * C + c) * BINS + oy * OUT_HW;
    o[0] = acc0 * ry / (float)(s_ex[0] - s_sx[0]);
    o[1] = acc1 * ry / (float)(s_ex[1] - s_sx[1]);
    o[2] = acc2 * ry / (float)(s_ex[2] - s_sx[2]);
    o[3] = acc3 * ry / (float)(s_ex[3] - s_sx[3]);
    o[4] = acc4 * ry / (float)(s_ex[4] - s_sx[4]);
    o[5] = acc5 * ry / (float)(s_ex[5] - s_sx[5]);
    o[6] = acc6 * ry / (float)(s_ex[6] - s_sx[6]);
}

extern "C" void kernel_launch(void* const* d_in, const int* in_sizes, int n_in,
                              void* d_out, int out_size, void* d_ws, size_t ws_size,
                              hipStream_t stream) {
    const float* x    = (const float*)d_in[0];
    const int*   rois = (const int*)d_in[1];
    float*       out  = (float*)d_out;
    const int B = 8, S = 128, H = 256, W = 256;
    roi_pool<<<dim3(B * S), dim3(448), 0, stream>>>(x, rois, out, H, W);
}

// Round 6
// 243.586 us; speedup vs baseline: 3.0571x; 3.0571x over previous
//
#include <hip/hip_runtime.h>

// ROI adaptive avg-pool 7x7, direct per-bin summation.
// x: [B=8, C=64, H=256, W=256] f32;  rois: [B, S=128, 5] i32 (idx,x1,y1,x2,y2)
// out: [B, S*C, 7, 7] f32 = out[((b*S+s)*C+c)*49 + oy*7+ox]
//
// R1 lesson: lanes sweeping adjacent bins within a channel is fetch-optimal
// (FETCH ~= logical 150 MB). R3 lesson: channel-in-lane-bits explodes fetch
// 10x. This round keeps R1's mapping and attacks latency instead:
//   - 4 chgroups/roi -> 4096 blocks (2x wave oversubscription, smooths
//     roi-size imbalance)
//   - 2-row x 2-col unrolled accumulators -> 4 independent load streams
//     per thread (R1 had VGPR=8, a single dependent chain).

constexpr int OUT_HW = 7;
constexpr int BINS = OUT_HW * OUT_HW;     // 49
constexpr int C = 64;
constexpr int CG = 4;                     // channel groups per roi
constexpr int CPG = C / CG;               // 16 channels per group
constexpr int ITEMS = CPG * BINS;         // 784 work items per block

__global__ __launch_bounds__(256) void roi_pool(
    const float* __restrict__ x, const int* __restrict__ rois,
    float* __restrict__ out, int H, int W)
{
    const int blk = blockIdx.x;
    const int bs  = blk >> 2;             // roi index (b*S+s)
    const int g   = blk & (CG - 1);       // channel group
    const int b   = bs >> 7;              // S = 128

    const int* r = rois + bs * 5;
    const int x1 = r[1], y1 = r[2], x2 = r[3], y2 = r[4];
    const int w = x2 - x1, h = y2 - y1;

    __shared__ int s_sy[OUT_HW], s_ey[OUT_HW], s_sx[OUT_HW], s_ex[OUT_HW];
    if (threadIdx.x < OUT_HW) {
        const int i = threadIdx.x;
        s_sy[i] = y1 + (i * h) / OUT_HW;
        s_ey[i] = y1 + ((i + 1) * h + OUT_HW - 1) / OUT_HW;
        s_sx[i] = x1 + (i * w) / OUT_HW;
        s_ex[i] = x1 + ((i + 1) * w + OUT_HW - 1) / OUT_HW;
    }
    __syncthreads();

    const int HW = H * W;
    const float* __restrict__ pc = x + ((size_t)b * C + g * CPG) * HW;
    float* __restrict__ ob = out + ((size_t)bs * C + g * CPG) * BINS;

    for (int o = threadIdx.x; o < ITEMS; o += 256) {
        const int c  = o / BINS;
        const int rr = o - c * BINS;
        const int oy = rr / OUT_HW;
        const int ox = rr - oy * OUT_HW;
        const int sy = s_sy[oy], ey = s_ey[oy];
        const int sx = s_sx[ox], ex = s_ex[ox];

        const float* __restrict__ p = pc + (size_t)c * HW;
        float a0 = 0.f, a1 = 0.f, a2 = 0.f, a3 = 0.f;

        int yy = sy;
        const float* row = p + (size_t)sy * W;
        for (; yy + 2 <= ey; yy += 2, row += 2 * W) {
            int xx = sx;
            for (; xx + 2 <= ex; xx += 2) {
                a0 += row[xx];
                a1 += row[xx + W];
                a2 += row[xx + 1];
                a3 += row[xx + W + 1];
            }
            if (xx < ex) { a0 += row[xx]; a1 += row[xx + W]; }
        }
        if (yy < ey) {
            int xx = sx;
            for (; xx + 2 <= ex; xx += 2) { a0 += row[xx]; a2 += row[xx + 1]; }
            if (xx < ex) a0 += row[xx];
        }

        const float sum = (a0 + a1) + (a2 + a3);
        ob[o] = sum / (float)((ey - sy) * (ex - sx));
    }
}

extern "C" void kernel_launch(void* const* d_in, const int* in_sizes, int n_in,
                              void* d_out, int out_size, void* d_ws, size_t ws_size,
                              hipStream_t stream) {
    const float* x    = (const float*)d_in[0];
    const int*   rois = (const int*)d_in[1];
    float*       out  = (float*)d_out;
    const int B = 8, S = 128, H = 256, W = 256;
    roi_pool<<<dim3(B * S * CG), dim3(256), 0, stream>>>(x, rois, out, H, W);
}